// Round 6
// baseline (396.838 us; speedup 1.0000x reference)
//
#include <hip/hip_runtime.h>
#include <stdint.h>

// FloodFillOperation: B=256, C=10, H=256, W=256 fp32
#define B_ 256
#define C_ 10
#define H_ 256
#define W_ 256
#define WPR 8            // 32-bit words per row (256 bits)
#define WPI 2048         // words per image bitmask (256 rows * 8)

typedef float f4 __attribute__((ext_vector_type(4)));

// spread 8 bits b[i] -> output bit 4i
__device__ __forceinline__ uint32_t spread4(uint32_t u) {
  u = (u | (u << 12)) & 0x000F000Fu;
  u = (u | (u << 6))  & 0x03030303u;
  u = (u | (u << 3))  & 0x11111111u;
  return u;
}

// ---------------- Kernel A: per-batch seed color ----------------
__global__ __launch_bounds__(256) void ff_seed_kernel(
    const float* __restrict__ grid,
    const int* __restrict__ p_sy, const int* __restrict__ p_sx,
    int* __restrict__ ws_sc, int* __restrict__ ws_has)
{
  const int b = blockIdx.x * 256 + threadIdx.x;
  if (b >= B_) return;
  const int sy = p_sy[0], sx = p_sx[0];
  int sc = 0, has = 0;
  #pragma unroll
  for (int c = C_ - 1; c >= 0; --c) {           // keeps LOWEST c with v>0.5
    float v = grid[(((size_t)b * C_ + c) * H_ + sy) * W_ + sx];
    if (v > 0.5f) { sc = c; has = 1; }
  }
  ws_sc[b] = sc;
  ws_has[b] = has;
}

// ---------------- Kernel B: seed-channel -> bitmask (full occupancy) ----------------
__global__ __launch_bounds__(256) void ff_bitmask_kernel(
    const float* __restrict__ grid,
    const int* __restrict__ ws_sc,
    uint32_t* __restrict__ ws_cm)
{
  const int lane = threadIdx.x & 63;
  const int wv   = threadIdx.x >> 6;
  int gw = blockIdx.x * 4 + wv;
  const int nw = gridDim.x * 4;
  const int nchunks = B_ * H_ * W_ / 256;   // 65536
  for (int ck = gw; ck < nchunks; ck += nw) {
    const int b   = ck >> 8;
    const int cof = ck & 255;
    const int sc  = ws_sc[b];
    const float* ch = grid + ((size_t)b * C_ + sc) * (size_t)(H_ * W_) + cof * 256;
    f4 v = ((const f4*)ch)[lane];
    unsigned long long bx = __ballot(v.x > 0.5f);
    unsigned long long by = __ballot(v.y > 0.5f);
    unsigned long long bz = __ballot(v.z > 0.5f);
    unsigned long long bw = __ballot(v.w > 0.5f);
    if (lane < 8) {
      uint32_t word = spread4((uint32_t)(bx >> (8 * lane)) & 0xFFu)
                    | (spread4((uint32_t)(by >> (8 * lane)) & 0xFFu) << 1)
                    | (spread4((uint32_t)(bz >> (8 * lane)) & 0xFFu) << 2)
                    | (spread4((uint32_t)(bw >> (8 * lane)) & 0xFFu) << 3);
      ws_cm[(size_t)b * WPI + cof * 8 + lane] = word;
    }
  }
}

// ---------------- Kernel C: per-batch flood fill, slab-parallel ----------------
__global__ __launch_bounds__(256) void ff_flood_kernel(
    const uint32_t* __restrict__ ws_cm,
    const int* __restrict__ ws_has,
    const int* __restrict__ p_sy, const int* __restrict__ p_sx,
    uint32_t* __restrict__ ws_mask)
{
  const int b = blockIdx.x, tid = threadIdx.x;
  const int lane = tid & 63;
  const int r = tid;                       // own row
  __shared__ uint32_t cm[WPI];
  __shared__ uint32_t m[WPI];
  __shared__ int s_changed;

  const int sy = p_sy[0], sx = p_sx[0];

  for (int i = tid; i < WPI; i += 256) {
    cm[(i & 7) * H_ + (i >> 3)] = ws_cm[(size_t)b * WPI + i];
    m[(i & 7) * H_ + (i >> 3)] = 0u;
  }
  if (tid == 0) {
    s_changed = 0;
    if (ws_has[b]) m[(sx >> 5) * H_ + sy] = 1u << (sx & 31);
  }
  __syncthreads();

  uint32_t cmr[WPR];
  #pragma unroll
  for (int j = 0; j < WPR; ++j) cmr[j] = cm[j * H_ + r];

  for (;;) {
    uint32_t w_[WPR], orig[WPR], abv[WPR], blw[WPR];
    #pragma unroll
    for (int j = 0; j < WPR; ++j) {
      w_[j] = m[j * H_ + r];
      orig[j] = w_[j];
      abv[j] = (lane == 0 && r > 0)        ? m[j * H_ + (r - 1)] : 0u;
      blw[j] = (lane == 63 && r < H_ - 1)  ? m[j * H_ + (r + 1)] : 0u;
    }

    // saturate slab: alternate horizontal saturation and one vertical shfl step
    for (;;) {
      bool hch = true;
      while (hch) {
        hch = false;
        #pragma unroll
        for (int j = 0; j < WPR; ++j) {
          uint32_t lo = (w_[j] << 1) | (j > 0       ? (w_[j - 1] >> 31) : 0u);
          uint32_t hi = (w_[j] >> 1) | (j < WPR - 1 ? (w_[j + 1] << 31) : 0u);
          uint32_t v = (w_[j] | lo | hi) & cmr[j];
          hch |= (v != w_[j]);
          w_[j] = v;
        }
        hch = __any(hch);
      }
      bool vch = false;
      #pragma unroll
      for (int j = 0; j < WPR; ++j) {
        uint32_t up = __shfl_up(w_[j], 1);
        if (lane == 0) up = abv[j];
        uint32_t dn = __shfl_down(w_[j], 1);
        if (lane == 63) dn = blw[j];
        uint32_t v = (w_[j] | up | dn) & cmr[j];
        vch |= (v != w_[j]);
        w_[j] = v;
      }
      if (!__any(vch)) break;
    }

    bool ch = false;
    #pragma unroll
    for (int j = 0; j < WPR; ++j) ch |= (w_[j] != orig[j]);
    if (ch) {
      #pragma unroll
      for (int j = 0; j < WPR; ++j) m[j * H_ + r] = w_[j];
      s_changed = 1;                 // benign race: any 1 wins
    }
    __syncthreads();                 // B1
    bool done = (s_changed == 0);
    __syncthreads();                 // B2
    if (done) break;
    if (tid == 0) s_changed = 0;
    __syncthreads();                 // B3
  }

  for (int i = tid; i < WPI; i += 256)
    ws_mask[(size_t)b * WPI + i] = m[(i & 7) * H_ + (i >> 3)];
}

// ---------------- Kernel D: grid-stride streaming copy (m13 pattern) ----------------
// 4096 blocks x 256 threads, 4 independent f4 loads in flight per thread.
__global__ __launch_bounds__(256) void ff_copy_kernel(
    const f4* __restrict__ gin, f4* __restrict__ gout, int n4)
{
  const int stride = gridDim.x * 256;
  int i = blockIdx.x * 256 + threadIdx.x;
  for (; i + 3 * stride < n4; i += 4 * stride) {
    f4 a = gin[i];
    f4 b = gin[i + stride];
    f4 c = gin[i + 2 * stride];
    f4 d = gin[i + 3 * stride];
    gout[i]              = a;
    gout[i + stride]     = b;
    gout[i + 2 * stride] = c;
    gout[i + 3 * stride] = d;
  }
  for (; i < n4; i += stride) gout[i] = gin[i];
}

// ---------------- Kernel E: scatter fixup of masked pixels ----------------
__global__ __launch_bounds__(256) void ff_fixup_kernel(
    float* __restrict__ out,
    const uint32_t* __restrict__ ws_mask,
    const int* __restrict__ ws_sc,
    const int* __restrict__ p_tc)
{
  const int b = blockIdx.x, tid = threadIdx.x;
  const int tc = p_tc[0];
  const int sc = ws_sc[b];
  float* osc = out + ((size_t)b * C_ + sc) * (size_t)(H_ * W_);
  float* otc = out + ((size_t)b * C_ + tc) * (size_t)(H_ * W_);
  const bool same = (sc == tc);
  #pragma unroll
  for (int k = 0; k < WPI / 256; ++k) {           // 8 words per thread
    const int i = k * 256 + tid;                  // word index
    uint32_t mw = ws_mask[(size_t)b * WPI + i];
    while (mw) {
      const int bit = __ffs(mw) - 1;
      mw &= mw - 1;
      const int pix = (i << 5) | bit;             // flat h*W+w
      if (!same) osc[pix] = 0.0f;
      otc[pix] = 1.0f;                             // target wins
    }
  }
}

extern "C" void kernel_launch(void* const* d_in, const int* in_sizes, int n_in,
                              void* d_out, int out_size, void* d_ws, size_t ws_size,
                              hipStream_t stream) {
  const float* grid = (const float*)d_in[0];
  const int* p_sy   = (const int*)d_in[1];
  const int* p_sx   = (const int*)d_in[2];
  const int* p_tc   = (const int*)d_in[3];
  float* out        = (float*)d_out;

  // workspace layout
  uint32_t* ws_mask = (uint32_t*)d_ws;                                    // 2 MB
  uint32_t* ws_cm   = (uint32_t*)((char*)d_ws + 2u * 1024 * 1024);        // 2 MB
  int* ws_sc        = (int*)((char*)d_ws + 4u * 1024 * 1024);             // 1 KB
  int* ws_has       = (int*)((char*)d_ws + 4u * 1024 * 1024 + 4096);      // 1 KB

  ff_seed_kernel<<<1, 256, 0, stream>>>(grid, p_sy, p_sx, ws_sc, ws_has);
  ff_bitmask_kernel<<<2048, 256, 0, stream>>>(grid, ws_sc, ws_cm);
  ff_flood_kernel<<<B_, 256, 0, stream>>>(ws_cm, ws_has, p_sy, p_sx, ws_mask);

  const int n4 = (B_ * C_ * H_ * W_) / 4;          // 16,777,216
  ff_copy_kernel<<<4096, 256, 0, stream>>>((const f4*)grid, (f4*)out, n4);
  ff_fixup_kernel<<<B_, 256, 0, stream>>>(out, ws_mask, ws_sc, p_tc);
}

// Round 8
// 307.823 us; speedup vs baseline: 1.2892x; 1.2892x over previous
//
#include <hip/hip_runtime.h>
#include <stdint.h>

// FloodFillOperation: B=256, C=10, H=256, W=256 fp32
#define B_ 256
#define C_ 10
#define H_ 256
#define W_ 256
#define WPR 8            // 32-bit words per row (256 bits)
#define WPI 2048         // words per image bitmask (256 rows * 8)
#define N4  (B_ * C_ * H_ * W_ / 4)   // 41,943,040 f4 elements

typedef float f4 __attribute__((ext_vector_type(4)));

// spread 8 bits b[i] -> output bit 4i
__device__ __forceinline__ uint32_t spread4(uint32_t u) {
  u = (u | (u << 12)) & 0x000F000Fu;
  u = (u | (u << 6))  & 0x03030303u;
  u = (u | (u << 3))  & 0x11111111u;
  return u;
}

// ---------------- Kernel A: per-batch seed color ----------------
__global__ __launch_bounds__(256) void ff_seed_kernel(
    const float* __restrict__ grid,
    const int* __restrict__ p_sy, const int* __restrict__ p_sx,
    int* __restrict__ ws_sc, int* __restrict__ ws_has)
{
  const int b = blockIdx.x * 256 + threadIdx.x;
  if (b >= B_) return;
  const int sy = p_sy[0], sx = p_sx[0];
  int sc = 0, has = 0;
  #pragma unroll
  for (int c = C_ - 1; c >= 0; --c) {           // keeps LOWEST c with v>0.5
    float v = grid[(((size_t)b * C_ + c) * H_ + sy) * W_ + sx];
    if (v > 0.5f) { sc = c; has = 1; }
  }
  ws_sc[b] = sc;
  ws_has[b] = has;
}

// ---------------- Kernel B: seed-channel -> bitmask (full occupancy) ----------------
__global__ __launch_bounds__(256) void ff_bitmask_kernel(
    const float* __restrict__ grid,
    const int* __restrict__ ws_sc,
    uint32_t* __restrict__ ws_cm)
{
  const int lane = threadIdx.x & 63;
  const int wv   = threadIdx.x >> 6;
  int gw = blockIdx.x * 4 + wv;
  const int nw = gridDim.x * 4;
  const int nchunks = B_ * H_ * W_ / 256;   // 65536
  for (int ck = gw; ck < nchunks; ck += nw) {
    const int b   = ck >> 8;
    const int cof = ck & 255;
    const int sc  = ws_sc[b];
    const float* ch = grid + ((size_t)b * C_ + sc) * (size_t)(H_ * W_) + cof * 256;
    f4 v = ((const f4*)ch)[lane];
    unsigned long long bx = __ballot(v.x > 0.5f);
    unsigned long long by = __ballot(v.y > 0.5f);
    unsigned long long bz = __ballot(v.z > 0.5f);
    unsigned long long bw = __ballot(v.w > 0.5f);
    if (lane < 8) {
      uint32_t word = spread4((uint32_t)(bx >> (8 * lane)) & 0xFFu)
                    | (spread4((uint32_t)(by >> (8 * lane)) & 0xFFu) << 1)
                    | (spread4((uint32_t)(bz >> (8 * lane)) & 0xFFu) << 2)
                    | (spread4((uint32_t)(bw >> (8 * lane)) & 0xFFu) << 3);
      ws_cm[(size_t)b * WPI + cof * 8 + lane] = word;
    }
  }
}

// ---------------- Kernel C: per-batch flood fill, slab-parallel ----------------
__global__ __launch_bounds__(256) void ff_flood_kernel(
    const uint32_t* __restrict__ ws_cm,
    const int* __restrict__ ws_has,
    const int* __restrict__ p_sy, const int* __restrict__ p_sx,
    uint32_t* __restrict__ ws_mask)
{
  const int b = blockIdx.x, tid = threadIdx.x;
  const int lane = tid & 63;
  const int r = tid;                       // own row
  __shared__ uint32_t cm[WPI];
  __shared__ uint32_t m[WPI];
  __shared__ int s_changed;

  const int sy = p_sy[0], sx = p_sx[0];

  for (int i = tid; i < WPI; i += 256) {
    cm[(i & 7) * H_ + (i >> 3)] = ws_cm[(size_t)b * WPI + i];
    m[(i & 7) * H_ + (i >> 3)] = 0u;
  }
  if (tid == 0) {
    s_changed = 0;
    if (ws_has[b]) m[(sx >> 5) * H_ + sy] = 1u << (sx & 31);
  }
  __syncthreads();

  uint32_t cmr[WPR];
  #pragma unroll
  for (int j = 0; j < WPR; ++j) cmr[j] = cm[j * H_ + r];

  for (;;) {
    uint32_t w_[WPR], orig[WPR], abv[WPR], blw[WPR];
    #pragma unroll
    for (int j = 0; j < WPR; ++j) {
      w_[j] = m[j * H_ + r];
      orig[j] = w_[j];
      abv[j] = (lane == 0 && r > 0)        ? m[j * H_ + (r - 1)] : 0u;
      blw[j] = (lane == 63 && r < H_ - 1)  ? m[j * H_ + (r + 1)] : 0u;
    }

    // saturate slab: alternate horizontal saturation and one vertical shfl step
    for (;;) {
      bool hch = true;
      while (hch) {
        hch = false;
        #pragma unroll
        for (int j = 0; j < WPR; ++j) {
          uint32_t lo = (w_[j] << 1) | (j > 0       ? (w_[j - 1] >> 31) : 0u);
          uint32_t hi = (w_[j] >> 1) | (j < WPR - 1 ? (w_[j + 1] << 31) : 0u);
          uint32_t v = (w_[j] | lo | hi) & cmr[j];
          hch |= (v != w_[j]);
          w_[j] = v;
        }
        hch = __any(hch);
      }
      bool vch = false;
      #pragma unroll
      for (int j = 0; j < WPR; ++j) {
        uint32_t up = __shfl_up(w_[j], 1);
        if (lane == 0) up = abv[j];
        uint32_t dn = __shfl_down(w_[j], 1);
        if (lane == 63) dn = blw[j];
        uint32_t v = (w_[j] | up | dn) & cmr[j];
        vch |= (v != w_[j]);
        w_[j] = v;
      }
      if (!__any(vch)) break;
    }

    bool ch = false;
    #pragma unroll
    for (int j = 0; j < WPR; ++j) ch |= (w_[j] != orig[j]);
    if (ch) {
      #pragma unroll
      for (int j = 0; j < WPR; ++j) m[j * H_ + r] = w_[j];
      s_changed = 1;                 // benign race: any 1 wins
    }
    __syncthreads();                 // B1
    bool done = (s_changed == 0);
    __syncthreads();                 // B2
    if (done) break;
    if (tid == 0) s_changed = 0;
    __syncthreads();                 // B3
  }

  for (int i = tid; i < WPI; i += 256)
    ws_mask[(size_t)b * WPI + i] = m[(i & 7) * H_ + (i >> 3)];
}

// ---------------- Kernel D: one-shot nontemporal copy, 4 f4 per thread ----------------
// 40960 blocks x 256 threads; block covers 1024 consecutive f4 (40960*1024 = N4
// exactly, no tail); lanes at base+{0,256,512,768} -> every instruction fully
// coalesced; 4 nt loads in flight then 4 nt stores.
__global__ __launch_bounds__(256) void ff_copy_kernel(
    const f4* __restrict__ gin, f4* __restrict__ gout)
{
  const int base = blockIdx.x * 1024 + threadIdx.x;
  f4 a = __builtin_nontemporal_load(&gin[base]);
  f4 b = __builtin_nontemporal_load(&gin[base + 256]);
  f4 c = __builtin_nontemporal_load(&gin[base + 512]);
  f4 d = __builtin_nontemporal_load(&gin[base + 768]);
  __builtin_nontemporal_store(a, &gout[base]);
  __builtin_nontemporal_store(b, &gout[base + 256]);
  __builtin_nontemporal_store(c, &gout[base + 512]);
  __builtin_nontemporal_store(d, &gout[base + 768]);
}

// ---------------- Kernel E: scatter fixup of masked pixels ----------------
__global__ __launch_bounds__(256) void ff_fixup_kernel(
    float* __restrict__ out,
    const uint32_t* __restrict__ ws_mask,
    const int* __restrict__ ws_sc,
    const int* __restrict__ p_tc)
{
  const int b = blockIdx.x, tid = threadIdx.x;
  const int tc = p_tc[0];
  const int sc = ws_sc[b];
  float* osc = out + ((size_t)b * C_ + sc) * (size_t)(H_ * W_);
  float* otc = out + ((size_t)b * C_ + tc) * (size_t)(H_ * W_);
  const bool same = (sc == tc);
  #pragma unroll
  for (int k = 0; k < WPI / 256; ++k) {           // 8 words per thread
    const int i = k * 256 + tid;                  // word index
    uint32_t mw = ws_mask[(size_t)b * WPI + i];
    while (mw) {
      const int bit = __ffs(mw) - 1;
      mw &= mw - 1;
      const int pix = (i << 5) | bit;             // flat h*W+w
      if (!same) osc[pix] = 0.0f;
      otc[pix] = 1.0f;                             // target wins
    }
  }
}

extern "C" void kernel_launch(void* const* d_in, const int* in_sizes, int n_in,
                              void* d_out, int out_size, void* d_ws, size_t ws_size,
                              hipStream_t stream) {
  const float* grid = (const float*)d_in[0];
  const int* p_sy   = (const int*)d_in[1];
  const int* p_sx   = (const int*)d_in[2];
  const int* p_tc   = (const int*)d_in[3];
  float* out        = (float*)d_out;

  // workspace layout
  uint32_t* ws_mask = (uint32_t*)d_ws;                                    // 2 MB
  uint32_t* ws_cm   = (uint32_t*)((char*)d_ws + 2u * 1024 * 1024);        // 2 MB
  int* ws_sc        = (int*)((char*)d_ws + 4u * 1024 * 1024);             // 1 KB
  int* ws_has       = (int*)((char*)d_ws + 4u * 1024 * 1024 + 4096);      // 1 KB

  ff_seed_kernel<<<1, 256, 0, stream>>>(grid, p_sy, p_sx, ws_sc, ws_has);
  ff_bitmask_kernel<<<2048, 256, 0, stream>>>(grid, ws_sc, ws_cm);
  ff_flood_kernel<<<B_, 256, 0, stream>>>(ws_cm, ws_has, p_sy, p_sx, ws_mask);

  ff_copy_kernel<<<N4 / 1024, 256, 0, stream>>>((const f4*)grid, (f4*)out);   // 40960 blocks
  ff_fixup_kernel<<<B_, 256, 0, stream>>>(out, ws_mask, ws_sc, p_tc);
}

// Round 9
// 307.188 us; speedup vs baseline: 1.2918x; 1.0021x over previous
//
#include <hip/hip_runtime.h>
#include <stdint.h>

// FloodFillOperation: B=256, C=10, H=256, W=256 fp32
#define B_ 256
#define C_ 10
#define H_ 256
#define W_ 256
#define WPR 8            // 32-bit words per row (256 bits)
#define WPI 2048         // words per image bitmask (256 rows * 8)
#define N4  (B_ * C_ * H_ * W_ / 4)   // 41,943,040 f4 elements

typedef float f4 __attribute__((ext_vector_type(4)));

// spread 8 bits b[i] -> output bit 4i
__device__ __forceinline__ uint32_t spread4(uint32_t u) {
  u = (u | (u << 12)) & 0x000F000Fu;
  u = (u | (u << 6))  & 0x03030303u;
  u = (u | (u << 3))  & 0x11111111u;
  return u;
}

// ---------------- Kernel A: per-batch seed color ----------------
__global__ __launch_bounds__(256) void ff_seed_kernel(
    const float* __restrict__ grid,
    const int* __restrict__ p_sy, const int* __restrict__ p_sx,
    int* __restrict__ ws_sc, int* __restrict__ ws_has)
{
  const int b = blockIdx.x * 256 + threadIdx.x;
  if (b >= B_) return;
  const int sy = p_sy[0], sx = p_sx[0];
  int sc = 0, has = 0;
  #pragma unroll
  for (int c = C_ - 1; c >= 0; --c) {           // keeps LOWEST c with v>0.5
    float v = grid[(((size_t)b * C_ + c) * H_ + sy) * W_ + sx];
    if (v > 0.5f) { sc = c; has = 1; }
  }
  ws_sc[b] = sc;
  ws_has[b] = has;
}

// ---------------- Kernel B: seed-channel -> bitmask (full occupancy) ----------------
__global__ __launch_bounds__(256) void ff_bitmask_kernel(
    const float* __restrict__ grid,
    const int* __restrict__ ws_sc,
    uint32_t* __restrict__ ws_cm)
{
  const int lane = threadIdx.x & 63;
  const int wv   = threadIdx.x >> 6;
  int gw = blockIdx.x * 4 + wv;
  const int nw = gridDim.x * 4;
  const int nchunks = B_ * H_ * W_ / 256;   // 65536
  for (int ck = gw; ck < nchunks; ck += nw) {
    const int b   = ck >> 8;
    const int cof = ck & 255;
    const int sc  = ws_sc[b];
    const float* ch = grid + ((size_t)b * C_ + sc) * (size_t)(H_ * W_) + cof * 256;
    f4 v = ((const f4*)ch)[lane];
    unsigned long long bx = __ballot(v.x > 0.5f);
    unsigned long long by = __ballot(v.y > 0.5f);
    unsigned long long bz = __ballot(v.z > 0.5f);
    unsigned long long bw = __ballot(v.w > 0.5f);
    if (lane < 8) {
      uint32_t word = spread4((uint32_t)(bx >> (8 * lane)) & 0xFFu)
                    | (spread4((uint32_t)(by >> (8 * lane)) & 0xFFu) << 1)
                    | (spread4((uint32_t)(bz >> (8 * lane)) & 0xFFu) << 2)
                    | (spread4((uint32_t)(bw >> (8 * lane)) & 0xFFu) << 3);
      ws_cm[(size_t)b * WPI + cof * 8 + lane] = word;
    }
  }
}

// ---------------- Kernel C: per-batch flood fill, slab-parallel ----------------
__global__ __launch_bounds__(256) void ff_flood_kernel(
    const uint32_t* __restrict__ ws_cm,
    const int* __restrict__ ws_has,
    const int* __restrict__ p_sy, const int* __restrict__ p_sx,
    uint32_t* __restrict__ ws_mask)
{
  const int b = blockIdx.x, tid = threadIdx.x;
  const int lane = tid & 63;
  const int r = tid;                       // own row
  __shared__ uint32_t cm[WPI];
  __shared__ uint32_t m[WPI];
  __shared__ int s_changed;

  const int sy = p_sy[0], sx = p_sx[0];

  for (int i = tid; i < WPI; i += 256) {
    cm[(i & 7) * H_ + (i >> 3)] = ws_cm[(size_t)b * WPI + i];
    m[(i & 7) * H_ + (i >> 3)] = 0u;
  }
  if (tid == 0) {
    s_changed = 0;
    if (ws_has[b]) m[(sx >> 5) * H_ + sy] = 1u << (sx & 31);
  }
  __syncthreads();

  uint32_t cmr[WPR];
  #pragma unroll
  for (int j = 0; j < WPR; ++j) cmr[j] = cm[j * H_ + r];

  for (;;) {
    uint32_t w_[WPR], orig[WPR], abv[WPR], blw[WPR];
    #pragma unroll
    for (int j = 0; j < WPR; ++j) {
      w_[j] = m[j * H_ + r];
      orig[j] = w_[j];
      abv[j] = (lane == 0 && r > 0)        ? m[j * H_ + (r - 1)] : 0u;
      blw[j] = (lane == 63 && r < H_ - 1)  ? m[j * H_ + (r + 1)] : 0u;
    }

    // saturate slab: alternate horizontal saturation and one vertical shfl step
    for (;;) {
      bool hch = true;
      while (hch) {
        hch = false;
        #pragma unroll
        for (int j = 0; j < WPR; ++j) {
          uint32_t lo = (w_[j] << 1) | (j > 0       ? (w_[j - 1] >> 31) : 0u);
          uint32_t hi = (w_[j] >> 1) | (j < WPR - 1 ? (w_[j + 1] << 31) : 0u);
          uint32_t v = (w_[j] | lo | hi) & cmr[j];
          hch |= (v != w_[j]);
          w_[j] = v;
        }
        hch = __any(hch);
      }
      bool vch = false;
      #pragma unroll
      for (int j = 0; j < WPR; ++j) {
        uint32_t up = __shfl_up(w_[j], 1);
        if (lane == 0) up = abv[j];
        uint32_t dn = __shfl_down(w_[j], 1);
        if (lane == 63) dn = blw[j];
        uint32_t v = (w_[j] | up | dn) & cmr[j];
        vch |= (v != w_[j]);
        w_[j] = v;
      }
      if (!__any(vch)) break;
    }

    bool ch = false;
    #pragma unroll
    for (int j = 0; j < WPR; ++j) ch |= (w_[j] != orig[j]);
    if (ch) {
      #pragma unroll
      for (int j = 0; j < WPR; ++j) m[j * H_ + r] = w_[j];
      s_changed = 1;                 // benign race: any 1 wins
    }
    __syncthreads();                 // B1
    bool done = (s_changed == 0);
    __syncthreads();                 // B2
    if (done) break;
    if (tid == 0) s_changed = 0;
    __syncthreads();                 // B3
  }

  for (int i = tid; i < WPI; i += 256)
    ws_mask[(size_t)b * WPI + i] = m[(i & 7) * H_ + (i >> 3)];
}

// ---------------- Kernel D: one-shot nontemporal copy, 4 f4 per thread ----------------
// 40960 blocks x 256 threads; block covers 1024 consecutive f4 (40960*1024 = N4
// exactly, no tail); lanes at base+{0,256,512,768} -> every instruction fully
// coalesced; 4 nt loads in flight then 4 nt stores.
__global__ __launch_bounds__(256) void ff_copy_kernel(
    const f4* __restrict__ gin, f4* __restrict__ gout)
{
  const int base = blockIdx.x * 1024 + threadIdx.x;
  f4 a = __builtin_nontemporal_load(&gin[base]);
  f4 b = __builtin_nontemporal_load(&gin[base + 256]);
  f4 c = __builtin_nontemporal_load(&gin[base + 512]);
  f4 d = __builtin_nontemporal_load(&gin[base + 768]);
  __builtin_nontemporal_store(a, &gout[base]);
  __builtin_nontemporal_store(b, &gout[base + 256]);
  __builtin_nontemporal_store(c, &gout[base + 512]);
  __builtin_nontemporal_store(d, &gout[base + 768]);
}

// ---------------- Kernel E: scatter fixup of masked pixels ----------------
__global__ __launch_bounds__(256) void ff_fixup_kernel(
    float* __restrict__ out,
    const uint32_t* __restrict__ ws_mask,
    const int* __restrict__ ws_sc,
    const int* __restrict__ p_tc)
{
  const int b = blockIdx.x, tid = threadIdx.x;
  const int tc = p_tc[0];
  const int sc = ws_sc[b];
  float* osc = out + ((size_t)b * C_ + sc) * (size_t)(H_ * W_);
  float* otc = out + ((size_t)b * C_ + tc) * (size_t)(H_ * W_);
  const bool same = (sc == tc);
  #pragma unroll
  for (int k = 0; k < WPI / 256; ++k) {           // 8 words per thread
    const int i = k * 256 + tid;                  // word index
    uint32_t mw = ws_mask[(size_t)b * WPI + i];
    while (mw) {
      const int bit = __ffs(mw) - 1;
      mw &= mw - 1;
      const int pix = (i << 5) | bit;             // flat h*W+w
      if (!same) osc[pix] = 0.0f;
      otc[pix] = 1.0f;                             // target wins
    }
  }
}

extern "C" void kernel_launch(void* const* d_in, const int* in_sizes, int n_in,
                              void* d_out, int out_size, void* d_ws, size_t ws_size,
                              hipStream_t stream) {
  const float* grid = (const float*)d_in[0];
  const int* p_sy   = (const int*)d_in[1];
  const int* p_sx   = (const int*)d_in[2];
  const int* p_tc   = (const int*)d_in[3];
  float* out        = (float*)d_out;

  // workspace layout
  uint32_t* ws_mask = (uint32_t*)d_ws;                                    // 2 MB
  uint32_t* ws_cm   = (uint32_t*)((char*)d_ws + 2u * 1024 * 1024);        // 2 MB
  int* ws_sc        = (int*)((char*)d_ws + 4u * 1024 * 1024);             // 1 KB
  int* ws_has       = (int*)((char*)d_ws + 4u * 1024 * 1024 + 4096);      // 1 KB

  ff_seed_kernel<<<1, 256, 0, stream>>>(grid, p_sy, p_sx, ws_sc, ws_has);
  ff_bitmask_kernel<<<2048, 256, 0, stream>>>(grid, ws_sc, ws_cm);
  ff_flood_kernel<<<B_, 256, 0, stream>>>(ws_cm, ws_has, p_sy, p_sx, ws_mask);

  ff_copy_kernel<<<N4 / 1024, 256, 0, stream>>>((const f4*)grid, (f4*)out);   // 40960 blocks
  ff_fixup_kernel<<<B_, 256, 0, stream>>>(out, ws_mask, ws_sc, p_tc);
}

// Round 10
// 274.070 us; speedup vs baseline: 1.4479x; 1.1208x over previous
//
#include <hip/hip_runtime.h>
#include <stdint.h>

// FloodFillOperation: B=256, C=10, H=256, W=256 fp32
#define B_ 256
#define C_ 10
#define H_ 256
#define W_ 256
#define WPR 8            // 32-bit words per row (256 bits)
#define WPI 2048         // words per image bitmask (256 rows * 8)
#define N4  (B_ * C_ * H_ * W_ / 4)   // 41,943,040 f4 elements

typedef float f4 __attribute__((ext_vector_type(4)));

// spread 8 bits b[i] -> output bit 4i
__device__ __forceinline__ uint32_t spread4(uint32_t u) {
  u = (u | (u << 12)) & 0x000F000Fu;
  u = (u | (u << 6))  & 0x03030303u;
  u = (u | (u << 3))  & 0x11111111u;
  return u;
}

// ---------------- Kernel A: per-batch seed color ----------------
__global__ __launch_bounds__(256) void ff_seed_kernel(
    const float* __restrict__ grid,
    const int* __restrict__ p_sy, const int* __restrict__ p_sx,
    int* __restrict__ ws_sc, int* __restrict__ ws_has)
{
  const int b = blockIdx.x * 256 + threadIdx.x;
  if (b >= B_) return;
  const int sy = p_sy[0], sx = p_sx[0];
  int sc = 0, has = 0;
  #pragma unroll
  for (int c = C_ - 1; c >= 0; --c) {           // keeps LOWEST c with v>0.5
    float v = grid[(((size_t)b * C_ + c) * H_ + sy) * W_ + sx];
    if (v > 0.5f) { sc = c; has = 1; }
  }
  ws_sc[b] = sc;
  ws_has[b] = has;
}

// ---------------- Kernel B: fused streaming copy + seed-channel bitmask ----------
// R5's best copy shape: one-shot, one f4 per thread, nontemporal, 163840 blocks.
// Each block covers 256 f4 = 1024 floats = 1/64 of one (b,c) plane. Blocks on
// the seed-color plane additionally ballot the values they already loaded.
__global__ __launch_bounds__(256) void ff_copy_bitmask_kernel(
    const f4* __restrict__ gin, f4* __restrict__ gout,
    const int* __restrict__ ws_sc,
    uint32_t* __restrict__ ws_cm)
{
  const int i = blockIdx.x * 256 + threadIdx.x;
  f4 v = __builtin_nontemporal_load(&gin[i]);
  __builtin_nontemporal_store(v, &gout[i]);

  const int bc = blockIdx.x >> 6;        // 64 blocks per (b,c) plane
  const int b  = bc / C_;
  const int c  = bc - b * C_;
  if (c == ws_sc[b]) {
    const int lane = threadIdx.x & 63;
    const int wv   = threadIdx.x >> 6;
    unsigned long long bx = __ballot(v.x > 0.5f);
    unsigned long long by = __ballot(v.y > 0.5f);
    unsigned long long bz = __ballot(v.z > 0.5f);
    unsigned long long bw = __ballot(v.w > 0.5f);
    if (lane < 8) {
      uint32_t word = spread4((uint32_t)(bx >> (8 * lane)) & 0xFFu)
                    | (spread4((uint32_t)(by >> (8 * lane)) & 0xFFu) << 1)
                    | (spread4((uint32_t)(bz >> (8 * lane)) & 0xFFu) << 2)
                    | (spread4((uint32_t)(bw >> (8 * lane)) & 0xFFu) << 3);
      // word index within image: ((block within plane)*1024 + wv*256)/32 + lane
      const int wbase = ((blockIdx.x & 63) << 5) + (wv << 3);
      ws_cm[(size_t)b * WPI + wbase + lane] = word;
    }
  }
}

// ---------------- Kernel C: per-batch flood fill + direct scatter to out ------
__global__ __launch_bounds__(256) void ff_flood_scatter_kernel(
    const uint32_t* __restrict__ ws_cm,
    const int* __restrict__ ws_sc,
    const int* __restrict__ ws_has,
    const int* __restrict__ p_sy, const int* __restrict__ p_sx,
    const int* __restrict__ p_tc,
    float* __restrict__ out)
{
  const int b = blockIdx.x, tid = threadIdx.x;
  const int lane = tid & 63;
  const int r = tid;                       // own row
  __shared__ uint32_t cm[WPI];
  __shared__ uint32_t m[WPI];
  __shared__ int s_changed;

  const int sy = p_sy[0], sx = p_sx[0];

  for (int i = tid; i < WPI; i += 256) {
    cm[(i & 7) * H_ + (i >> 3)] = ws_cm[(size_t)b * WPI + i];
    m[(i & 7) * H_ + (i >> 3)] = 0u;
  }
  if (tid == 0) {
    s_changed = 0;
    if (ws_has[b]) m[(sx >> 5) * H_ + sy] = 1u << (sx & 31);
  }
  __syncthreads();

  uint32_t cmr[WPR];
  #pragma unroll
  for (int j = 0; j < WPR; ++j) cmr[j] = cm[j * H_ + r];

  uint32_t w_[WPR];
  for (;;) {
    uint32_t orig[WPR], abv[WPR], blw[WPR];
    #pragma unroll
    for (int j = 0; j < WPR; ++j) {
      w_[j] = m[j * H_ + r];
      orig[j] = w_[j];
      abv[j] = (lane == 0 && r > 0)        ? m[j * H_ + (r - 1)] : 0u;
      blw[j] = (lane == 63 && r < H_ - 1)  ? m[j * H_ + (r + 1)] : 0u;
    }

    // saturate slab: alternate horizontal saturation and one vertical shfl step
    for (;;) {
      bool hch = true;
      while (hch) {
        hch = false;
        #pragma unroll
        for (int j = 0; j < WPR; ++j) {
          uint32_t lo = (w_[j] << 1) | (j > 0       ? (w_[j - 1] >> 31) : 0u);
          uint32_t hi = (w_[j] >> 1) | (j < WPR - 1 ? (w_[j + 1] << 31) : 0u);
          uint32_t v = (w_[j] | lo | hi) & cmr[j];
          hch |= (v != w_[j]);
          w_[j] = v;
        }
        hch = __any(hch);
      }
      bool vch = false;
      #pragma unroll
      for (int j = 0; j < WPR; ++j) {
        uint32_t up = __shfl_up(w_[j], 1);
        if (lane == 0) up = abv[j];
        uint32_t dn = __shfl_down(w_[j], 1);
        if (lane == 63) dn = blw[j];
        uint32_t v = (w_[j] | up | dn) & cmr[j];
        vch |= (v != w_[j]);
        w_[j] = v;
      }
      if (!__any(vch)) break;
    }

    bool ch = false;
    #pragma unroll
    for (int j = 0; j < WPR; ++j) ch |= (w_[j] != orig[j]);
    if (ch) {
      #pragma unroll
      for (int j = 0; j < WPR; ++j) m[j * H_ + r] = w_[j];
      s_changed = 1;                 // benign race: any 1 wins
    }
    __syncthreads();                 // B1
    bool done = (s_changed == 0);
    __syncthreads();                 // B2
    if (done) break;
    if (tid == 0) s_changed = 0;
    __syncthreads();                 // B3
  }

  // Scatter: w_ holds the fixpoint mask for row r (w_ == m at exit).
  // Write 0.0 to seed plane, 1.0 to target plane (target wins if same plane).
  const int tc = p_tc[0];
  const int sc = ws_sc[b];
  const bool same = (sc == tc);
  float* osc = out + ((size_t)b * C_ + sc) * (size_t)(H_ * W_);
  float* otc = out + ((size_t)b * C_ + tc) * (size_t)(H_ * W_);
  #pragma unroll
  for (int j = 0; j < WPR; ++j) {
    uint32_t mw = w_[j];
    while (mw) {
      const int bit = __ffs(mw) - 1;
      mw &= mw - 1;
      const int pix = r * W_ + (j << 5) + bit;
      if (!same) osc[pix] = 0.0f;
      otc[pix] = 1.0f;
    }
  }
}

extern "C" void kernel_launch(void* const* d_in, const int* in_sizes, int n_in,
                              void* d_out, int out_size, void* d_ws, size_t ws_size,
                              hipStream_t stream) {
  const float* grid = (const float*)d_in[0];
  const int* p_sy   = (const int*)d_in[1];
  const int* p_sx   = (const int*)d_in[2];
  const int* p_tc   = (const int*)d_in[3];
  float* out        = (float*)d_out;

  // workspace layout
  uint32_t* ws_cm   = (uint32_t*)d_ws;                                    // 2 MB
  int* ws_sc        = (int*)((char*)d_ws + 2u * 1024 * 1024);             // 1 KB
  int* ws_has       = (int*)((char*)d_ws + 2u * 1024 * 1024 + 4096);      // 1 KB

  ff_seed_kernel<<<1, 256, 0, stream>>>(grid, p_sy, p_sx, ws_sc, ws_has);
  ff_copy_bitmask_kernel<<<N4 / 256, 256, 0, stream>>>(
      (const f4*)grid, (f4*)out, ws_sc, ws_cm);          // 163840 blocks
  ff_flood_scatter_kernel<<<B_, 256, 0, stream>>>(
      ws_cm, ws_sc, ws_has, p_sy, p_sx, p_tc, out);
}